// Round 7
// baseline (251.491 us; speedup 1.0000x reference)
//
#include <hip/hip_runtime.h>

typedef float f32x4 __attribute__((ext_vector_type(4)));
typedef unsigned int uint32;

#define MAXV 51200            // bitmap capacity; V=50257 fits
#define NWMAX (MAXV / 32 + 1) // 1601 words (+1 pad for spanning reads)
#define LPAD 1024             // sorted-list capacity (L=400 fits)

// ---------------------------------------------------------------------------
// Prep: per source column b, sort (v, l) pairs ascending by (v, l) via O(L^2)
// rank sort. Row-independent (rows share columns mod B). Last-occurrence-wins
// falls out of upper_bound search later (max l sorts last among equal v).
// ---------------------------------------------------------------------------
__global__ __launch_bounds__(256) void sort_kernel(
    const int* __restrict__ sources, int* __restrict__ sv, int* __restrict__ sl,
    int L, int B, int V)
{
    const int b = blockIdx.x;
    __shared__ int s_col[LPAD];
    for (int l = threadIdx.x; l < L; l += 256) {
        const int v = sources[(size_t)l * B + b];
        s_col[l] = (v >= 0 && v < V) ? v : 0x7FFFFFFF;   // mode="drop"
    }
    __syncthreads();
    int* __restrict__ svb = sv + (size_t)b * L;
    int* __restrict__ slb = sl + (size_t)b * L;
    for (int l = threadIdx.x; l < L; l += 256) {
        const int v = s_col[l];
        int rank = 0;
        for (int k = 0; k < L; ++k) {
            const int vk = s_col[k];
            rank += (vk < v) || (vk == v && k < l);
        }
        svb[rank] = v;
        slb[rank] = l;
    }
}

// ---------------------------------------------------------------------------
// Fused single-pass: out[row,j] = pg*vd[row,j] (+ gate*attns[row,l] on the
// ~L scattered slots; last occurrence wins). One block per row; NT stores.
// Hot loop restructured to 8-deep two-phase bursts: 8 back-to-back loads,
// then 8 compute+store — longer same-direction memory runs per wave.
// ---------------------------------------------------------------------------
__global__ __launch_bounds__(256) void fused_kernel(
    const float* __restrict__ vd, const float* __restrict__ attns,
    const float* __restrict__ pgs, const int* __restrict__ sv,
    const int* __restrict__ sl, float* __restrict__ out, int V, int L, int B)
{
    const int row = blockIdx.x;
    const int tid = threadIdx.x;
    const int b   = row % B;

    __shared__ uint32 bm[NWMAX];
    __shared__ int    s_v[LPAD];
    __shared__ int    s_l[LPAD];
    __shared__ float  s_attn[LPAD];

    const int NW = (V + 31) >> 5;
    for (int w = tid; w < NW + 1; w += 256) bm[w] = 0u;
    const int* __restrict__ svb = sv + (size_t)b * L;
    const int* __restrict__ slb = sl + (size_t)b * L;
    for (int t = tid; t < LPAD; t += 256) {
        s_v[t]    = (t < L) ? svb[t] : 0x7FFFFFFF;
        s_l[t]    = (t < L) ? slb[t] : 0;
        s_attn[t] = (t < L) ? attns[(size_t)row * L + t] : 0.0f;
    }
    __syncthreads();
    for (int t = tid; t < L; t += 256) {
        const int v = s_v[t];
        if (v < V) atomicOr(&bm[v >> 5], 1u << (v & 31));
    }
    __syncthreads();

    const float pg   = pgs[row];
    const float gate = 1.0f - pg;
    const size_t base = (size_t)row * (size_t)V;

    // upper_bound(j) - 1 => last entry with s_v==j => max l => last-wins
    auto lookup = [&](int j) -> float {
        int lo = 0, hi = LPAD;
        while (lo < hi) {
            const int mid = (lo + hi) >> 1;
            if (s_v[mid] <= j) lo = mid + 1; else hi = mid;
        }
        return gate * s_attn[s_l[lo - 1]];
    };

    // peel to 16B alignment (V odd -> base mod 4 rotates per row)
    const int mis  = (int)(base & 3);
    const int pre  = mis ? (4 - mis) : 0;
    const int preN = pre < V ? pre : V;
    if (tid < preN) {
        const int j = tid;
        float x = pg * vd[base + j];
        if ((bm[j >> 5] >> (j & 31)) & 1u) x += lookup(j);
        __builtin_nontemporal_store(x, &out[base + j]);
    }

    const int nvec = (V - preN) >> 2;
    const f32x4* __restrict__ v4 = (const f32x4*)(vd + base + preN);
    f32x4* __restrict__ o4       = (f32x4*)(out + base + preN);

    // compute + NT-store one vector (value already loaded)
    auto finish = [&](f32x4 x, int i) {
        x *= pg;
        const int j0 = preN + (i << 2);
        const int w  = j0 >> 5;
        const uint32 sh = (uint32)(j0 & 31);
        uint32 bits;
        if (sh <= 28u) bits = (bm[w] >> sh) & 0xFu;
        else           bits = ((bm[w] >> sh) | (bm[w + 1] << (32u - sh))) & 0xFu;
        if (bits) {
#pragma unroll
            for (int e = 0; e < 4; ++e)
                if ((bits >> e) & 1u) x[e] += lookup(j0 + e);
        }
        __builtin_nontemporal_store(x, &o4[i]);
    };

    int i = tid;
    for (; i + 7 * 256 < nvec; i += 8 * 256) {
        // phase A: 8 independent loads issued back-to-back
        f32x4 x0 = v4[i];
        f32x4 x1 = v4[i + 256];
        f32x4 x2 = v4[i + 512];
        f32x4 x3 = v4[i + 768];
        f32x4 x4_ = v4[i + 1024];
        f32x4 x5 = v4[i + 1280];
        f32x4 x6 = v4[i + 1536];
        f32x4 x7 = v4[i + 1792];
        // phase B: 8 compute + NT stores back-to-back
        finish(x0, i);
        finish(x1, i + 256);
        finish(x2, i + 512);
        finish(x3, i + 768);
        finish(x4_, i + 1024);
        finish(x5, i + 1280);
        finish(x6, i + 1536);
        finish(x7, i + 1792);
    }
    for (; i < nvec; i += 256) finish(v4[i], i);

    for (int j = preN + (nvec << 2) + tid; j < V; j += 256) {
        float x = pg * vd[base + j];
        if ((bm[j >> 5] >> (j & 31)) & 1u) x += lookup(j);
        __builtin_nontemporal_store(x, &out[base + j]);
    }
}

// ---------------------------------------------------------------------------
// Fallback (round-1 fused kernel, verified correct) if ws/V/L out of bounds.
// ---------------------------------------------------------------------------
__global__ __launch_bounds__(256) void fused_fallback_kernel(
    const float* __restrict__ vocab_ds, const float* __restrict__ attns,
    const float* __restrict__ p_gens, const int* __restrict__ sources,
    float* __restrict__ out, int V, int L, int B)
{
    const int row = blockIdx.x;
    const int tid = threadIdx.x;
    const size_t base = (size_t)row * (size_t)V;
    const float pg = p_gens[row];

    const int mis  = (int)(base & 3);
    const int pre  = mis ? (4 - mis) : 0;
    const int preN = pre < V ? pre : V;
    for (int j = tid; j < preN; j += blockDim.x)
        out[base + j] = pg * vocab_ds[base + j];
    const int nvec = (V - preN) >> 2;
    const f32x4* __restrict__ v4 = (const f32x4*)(vocab_ds + base + preN);
    f32x4* __restrict__ o4       = (f32x4*)(out + base + preN);
    for (int i = tid; i < nvec; i += blockDim.x) {
        f32x4 x = v4[i];
        x *= pg;
        o4[i] = x;
    }
    for (int j = preN + (nvec << 2) + tid; j < V; j += blockDim.x)
        out[base + j] = pg * vocab_ds[base + j];

    __shared__ int s_src[512];
    const int b = row % B;
    const bool use_lds = (L <= 512);
    if (use_lds) {
        for (int l = tid; l < L; l += blockDim.x)
            s_src[l] = sources[(size_t)l * B + b];
    }
    __syncthreads();
    const float gate = 1.0f - pg;
    for (int l = tid; l < L; l += blockDim.x) {
        const int v = use_lds ? s_src[l] : sources[(size_t)l * B + b];
        if (v < 0 || v >= V) continue;
        bool last = true;
        for (int l2 = l + 1; l2 < L; ++l2) {
            const int v2 = use_lds ? s_src[l2] : sources[(size_t)l2 * B + b];
            if (v2 == v) { last = false; break; }
        }
        if (last) {
            const float a = gate * attns[(size_t)row * L + l];
            out[base + v] = pg * vocab_ds[base + v] + a;
        }
    }
}

extern "C" void kernel_launch(void* const* d_in, const int* in_sizes, int n_in,
                              void* d_out, int out_size, void* d_ws, size_t ws_size,
                              hipStream_t stream) {
    const float* vocab_ds = (const float*)d_in[0];
    const float* attns    = (const float*)d_in[1];
    const float* p_gens   = (const float*)d_in[2];
    const int*   sources  = (const int*)d_in[3];
    const int rows = in_sizes[2];
    const int V    = in_sizes[0] / rows;
    const int L    = in_sizes[1] / rows;
    const int B    = in_sizes[3] / L;
    float* out = (float*)d_out;

    const size_t need = (size_t)B * (size_t)L * 2 * sizeof(int);
    const bool fits = (ws_size >= need) && (V <= (NWMAX - 1) * 32) && (L <= LPAD);
    if (fits) {
        int* sv = (int*)d_ws;
        int* sl = sv + (size_t)B * (size_t)L;
        sort_kernel<<<B, 256, 0, stream>>>(sources, sv, sl, L, B, V);
        fused_kernel<<<rows, 256, 0, stream>>>(vocab_ds, attns, p_gens,
                                               sv, sl, out, V, L, B);
    } else {
        fused_fallback_kernel<<<rows, 256, 0, stream>>>(
            vocab_ds, attns, p_gens, sources, out, V, L, B);
    }
}

// Round 8
// 249.457 us; speedup vs baseline: 1.0082x; 1.0082x over previous
//
#include <hip/hip_runtime.h>

typedef float f32x4 __attribute__((ext_vector_type(4)));
typedef unsigned int uint32;

#define MAXV 51200            // bitmap capacity; V=50257 fits
#define NWMAX (MAXV / 32 + 1) // 1601 words (+1 pad for spanning reads)
#define LPAD 1024             // sorted-list capacity (L=400 fits)

// ---------------------------------------------------------------------------
// Prep: per source column b, sort (v, l) pairs ascending by (v, l) via O(L^2)
// rank sort. Row-independent (rows share columns mod B). Last-occurrence-wins
// falls out of upper_bound search later (max l sorts last among equal v).
// ---------------------------------------------------------------------------
__global__ __launch_bounds__(256) void sort_kernel(
    const int* __restrict__ sources, int* __restrict__ sv, int* __restrict__ sl,
    int L, int B, int V)
{
    const int b = blockIdx.x;
    __shared__ int s_col[LPAD];
    for (int l = threadIdx.x; l < L; l += 256) {
        const int v = sources[(size_t)l * B + b];
        s_col[l] = (v >= 0 && v < V) ? v : 0x7FFFFFFF;   // mode="drop"
    }
    __syncthreads();
    int* __restrict__ svb = sv + (size_t)b * L;
    int* __restrict__ slb = sl + (size_t)b * L;
    for (int l = threadIdx.x; l < L; l += 256) {
        const int v = s_col[l];
        int rank = 0;
        for (int k = 0; k < L; ++k) {
            const int vk = s_col[k];
            rank += (vk < v) || (vk == v && k < l);
        }
        svb[rank] = v;
        slb[rank] = l;
    }
}

// ---------------------------------------------------------------------------
// Fused single-pass: out[row,j] = pg*vd[row,j] (+ gate*attns[row,l] on the
// ~L scattered slots; last occurrence wins). One block per row; NT stores.
// Hot loop: register-rotation software pipeline — next batch's 4 loads are
// issued BEFORE the current batch is consumed/stored, so the compiler's wait
// for batch k+1 is a counted vmcnt that never force-drains the NT stores
// (stores get >=2 iterations of ack slack). R6's serial loop (VGPR=12) paid
// store-ack latency in every iteration's vmcnt(0).
// ---------------------------------------------------------------------------
__global__ __launch_bounds__(256) void fused_kernel(
    const float* __restrict__ vd, const float* __restrict__ attns,
    const float* __restrict__ pgs, const int* __restrict__ sv,
    const int* __restrict__ sl, float* __restrict__ out, int V, int L, int B)
{
    const int row = blockIdx.x;
    const int tid = threadIdx.x;
    const int b   = row % B;

    __shared__ uint32 bm[NWMAX];
    __shared__ int    s_v[LPAD];
    __shared__ int    s_l[LPAD];
    __shared__ float  s_attn[LPAD];

    const int NW = (V + 31) >> 5;
    for (int w = tid; w < NW + 1; w += 256) bm[w] = 0u;
    const int* __restrict__ svb = sv + (size_t)b * L;
    const int* __restrict__ slb = sl + (size_t)b * L;
    for (int t = tid; t < LPAD; t += 256) {
        s_v[t]    = (t < L) ? svb[t] : 0x7FFFFFFF;
        s_l[t]    = (t < L) ? slb[t] : 0;
        s_attn[t] = (t < L) ? attns[(size_t)row * L + t] : 0.0f;
    }
    __syncthreads();
    for (int t = tid; t < L; t += 256) {
        const int v = s_v[t];
        if (v < V) atomicOr(&bm[v >> 5], 1u << (v & 31));
    }
    __syncthreads();

    const float pg   = pgs[row];
    const float gate = 1.0f - pg;
    const size_t base = (size_t)row * (size_t)V;

    // upper_bound(j) - 1 => last entry with s_v==j => max l => last-wins
    auto lookup = [&](int j) -> float {
        int lo = 0, hi = LPAD;
        while (lo < hi) {
            const int mid = (lo + hi) >> 1;
            if (s_v[mid] <= j) lo = mid + 1; else hi = mid;
        }
        return gate * s_attn[s_l[lo - 1]];
    };

    // peel to 16B alignment (V odd -> base mod 4 rotates per row)
    const int mis  = (int)(base & 3);
    const int pre  = mis ? (4 - mis) : 0;
    const int preN = pre < V ? pre : V;
    if (tid < preN) {
        const int j = tid;
        float x = pg * vd[base + j];
        if ((bm[j >> 5] >> (j & 31)) & 1u) x += lookup(j);
        __builtin_nontemporal_store(x, &out[base + j]);
    }

    const int nvec = (V - preN) >> 2;
    const f32x4* __restrict__ v4 = (const f32x4*)(vd + base + preN);
    f32x4* __restrict__ o4       = (f32x4*)(out + base + preN);

    // compute + NT-store one vector (value already loaded)
    auto finish = [&](f32x4 x, int i) {
        x *= pg;
        const int j0 = preN + (i << 2);
        const int w  = j0 >> 5;
        const uint32 sh = (uint32)(j0 & 31);
        uint32 bits;
        if (sh <= 28u) bits = (bm[w] >> sh) & 0xFu;
        else           bits = ((bm[w] >> sh) | (bm[w + 1] << (32u - sh))) & 0xFu;
        if (bits) {
#pragma unroll
            for (int e = 0; e < 4; ++e)
                if ((bits >> e) & 1u) x[e] += lookup(j0 + e);
        }
        __builtin_nontemporal_store(x, &o4[i]);
    };

    int i = tid;
    if (i + 768 < nvec) {
        // prologue: load batch 0
        f32x4 c0 = v4[i];
        f32x4 c1 = v4[i + 256];
        f32x4 c2 = v4[i + 512];
        f32x4 c3 = v4[i + 768];
        int ip = i;
        // steady state: issue next batch's loads BEFORE consuming current
        for (i += 1024; i + 768 < nvec; i += 1024) {
            f32x4 n0 = v4[i];
            f32x4 n1 = v4[i + 256];
            f32x4 n2 = v4[i + 512];
            f32x4 n3 = v4[i + 768];
            finish(c0, ip);
            finish(c1, ip + 256);
            finish(c2, ip + 512);
            finish(c3, ip + 768);
            c0 = n0; c1 = n1; c2 = n2; c3 = n3;
            ip = i;
        }
        // epilogue: drain last batch
        finish(c0, ip);
        finish(c1, ip + 256);
        finish(c2, ip + 512);
        finish(c3, ip + 768);
        i = ip + 1024;
    }
    for (; i < nvec; i += 256) finish(v4[i], i);

    for (int j = preN + (nvec << 2) + tid; j < V; j += 256) {
        float x = pg * vd[base + j];
        if ((bm[j >> 5] >> (j & 31)) & 1u) x += lookup(j);
        __builtin_nontemporal_store(x, &out[base + j]);
    }
}

// ---------------------------------------------------------------------------
// Fallback (round-1 fused kernel, verified correct) if ws/V/L out of bounds.
// ---------------------------------------------------------------------------
__global__ __launch_bounds__(256) void fused_fallback_kernel(
    const float* __restrict__ vocab_ds, const float* __restrict__ attns,
    const float* __restrict__ p_gens, const int* __restrict__ sources,
    float* __restrict__ out, int V, int L, int B)
{
    const int row = blockIdx.x;
    const int tid = threadIdx.x;
    const size_t base = (size_t)row * (size_t)V;
    const float pg = p_gens[row];

    const int mis  = (int)(base & 3);
    const int pre  = mis ? (4 - mis) : 0;
    const int preN = pre < V ? pre : V;
    for (int j = tid; j < preN; j += blockDim.x)
        out[base + j] = pg * vocab_ds[base + j];
    const int nvec = (V - preN) >> 2;
    const f32x4* __restrict__ v4 = (const f32x4*)(vocab_ds + base + preN);
    f32x4* __restrict__ o4       = (f32x4*)(out + base + preN);
    for (int i = tid; i < nvec; i += blockDim.x) {
        f32x4 x = v4[i];
        x *= pg;
        o4[i] = x;
    }
    for (int j = preN + (nvec << 2) + tid; j < V; j += blockDim.x)
        out[base + j] = pg * vocab_ds[base + j];

    __shared__ int s_src[512];
    const int b = row % B;
    const bool use_lds = (L <= 512);
    if (use_lds) {
        for (int l = tid; l < L; l += blockDim.x)
            s_src[l] = sources[(size_t)l * B + b];
    }
    __syncthreads();
    const float gate = 1.0f - pg;
    for (int l = tid; l < L; l += blockDim.x) {
        const int v = use_lds ? s_src[l] : sources[(size_t)l * B + b];
        if (v < 0 || v >= V) continue;
        bool last = true;
        for (int l2 = l + 1; l2 < L; ++l2) {
            const int v2 = use_lds ? s_src[l2] : sources[(size_t)l2 * B + b];
            if (v2 == v) { last = false; break; }
        }
        if (last) {
            const float a = gate * attns[(size_t)row * L + l];
            out[base + v] = pg * vocab_ds[base + v] + a;
        }
    }
}

extern "C" void kernel_launch(void* const* d_in, const int* in_sizes, int n_in,
                              void* d_out, int out_size, void* d_ws, size_t ws_size,
                              hipStream_t stream) {
    const float* vocab_ds = (const float*)d_in[0];
    const float* attns    = (const float*)d_in[1];
    const float* p_gens   = (const float*)d_in[2];
    const int*   sources  = (const int*)d_in[3];
    const int rows = in_sizes[2];
    const int V    = in_sizes[0] / rows;
    const int L    = in_sizes[1] / rows;
    const int B    = in_sizes[3] / L;
    float* out = (float*)d_out;

    const size_t need = (size_t)B * (size_t)L * 2 * sizeof(int);
    const bool fits = (ws_size >= need) && (V <= (NWMAX - 1) * 32) && (L <= LPAD);
    if (fits) {
        int* sv = (int*)d_ws;
        int* sl = sv + (size_t)B * (size_t)L;
        sort_kernel<<<B, 256, 0, stream>>>(sources, sv, sl, L, B, V);
        fused_kernel<<<rows, 256, 0, stream>>>(vocab_ds, attns, p_gens,
                                               sv, sl, out, V, L, B);
    } else {
        fused_fallback_kernel<<<rows, 256, 0, stream>>>(
            vocab_ds, attns, p_gens, sources, out, V, L, B);
    }
}